// Round 12
// baseline (333.159 us; speedup 1.0000x reference)
//
#include <hip/hip_runtime.h>
#include <stdint.h>

#define Bb 2
#define Td 2048
#define Sd 2048
#define Dd 2048
#define Nh 16
#define Kvh 4
#define Hd 128
// G = Nh/Kvh = 4

typedef unsigned short u16;
typedef short bf16x8 __attribute__((ext_vector_type(8)));
typedef float f32x4 __attribute__((ext_vector_type(4)));

__device__ __forceinline__ u16 f2bf(float f) {
  union { float f; unsigned u; } v; v.f = f;
  v.u += 0x7FFF + ((v.u >> 16) & 1);   // round-to-nearest-even
  return (u16)(v.u >> 16);
}
__device__ __forceinline__ float bf2f(u16 h) {
  union { unsigned u; float f; } v; v.u = ((unsigned)h) << 16;
  return v.f;
}
// pack two f32 -> one u32 of 2 bf16 (lo in bits 15:0), RNE
__device__ __forceinline__ uint32_t cvtpk_bf16(float lo, float hi2) {
  uint32_t r;
  asm("v_cvt_pk_bf16_f32 %0, %1, %2" : "=v"(r) : "v"(lo), "v"(hi2));
  return r;
}

// ---------------- fused f32 -> bf16 convert for Xq and Xkv -----------------
__global__ __launch_bounds__(256) void k_convert2(const float* __restrict__ in1,
                                                  const float* __restrict__ in2,
                                                  u16* __restrict__ out1,
                                                  u16* __restrict__ out2, int n8each) {
  int i = blockIdx.x * 256 + threadIdx.x;
  const float* in = in1;
  u16* out = out1;
  if (i >= n8each) { i -= n8each; in = in2; out = out2; }
  const float4* p = (const float4*)in;
  float4 a = p[(size_t)i * 2], b = p[(size_t)i * 2 + 1];
  ushort4 r0, r1;
  r0.x = f2bf(a.x); r0.y = f2bf(a.y); r0.z = f2bf(a.z); r0.w = f2bf(a.w);
  r1.x = f2bf(b.x); r1.y = f2bf(b.y); r1.z = f2bf(b.z); r1.w = f2bf(b.w);
  ((ushort4*)out)[(size_t)i * 2] = r0;
  ((ushort4*)out)[(size_t)i * 2 + 1] = r1;
}

// -------- fused weight transposes: z=0 Wq, 1 Wo, 2 Wk, 3 Wv ---------------
__global__ __launch_bounds__(256) void k_transpose_w(const float* __restrict__ Wq,
                                                     const float* __restrict__ Wo,
                                                     const float* __restrict__ Wk,
                                                     const float* __restrict__ Wv,
                                                     u16* __restrict__ WqT,
                                                     u16* __restrict__ WoT,
                                                     u16* __restrict__ BtKV) {
  __shared__ u16 tile[32][33];
  int z = blockIdx.z;
  const float* in;
  u16* out;
  int R, C;
  if (z == 0)      { in = Wq; out = WqT; R = Dd; C = Nh * Hd; }
  else if (z == 1) { in = Wo; out = WoT; R = Nh * Hd; C = Dd; }
  else if (z == 2) { in = Wk; out = BtKV; R = Dd; C = Kvh * Hd; }
  else             { in = Wv; out = BtKV + (size_t)512 * Dd; R = Dd; C = Kvh * Hd; }
  int c0 = blockIdx.x * 32, r0 = blockIdx.y * 32;
  if (c0 >= C) return;
  int tx = threadIdx.x & 31, ty = threadIdx.x >> 5;  // 32 x 8
#pragma unroll
  for (int i = 0; i < 32; i += 8)
    tile[ty + i][tx] = f2bf(in[(size_t)(r0 + ty + i) * C + c0 + tx]);
  __syncthreads();
#pragma unroll
  for (int i = 0; i < 32; i += 8)
    out[(size_t)(c0 + ty + i) * R + r0 + tx] = tile[tx][ty + i];
}

// ---------------- V[B,S,Kvh,H] -> Vt[B,Kvh,H,S] (bf16) ---------------------
__global__ __launch_bounds__(256) void k_transpose_v(const u16* __restrict__ in,
                                                     u16* __restrict__ out) {
  __shared__ u16 tile[32][33];
  int bkh = blockIdx.z;
  int b = bkh >> 2, kh = bkh & 3;
  int h0 = blockIdx.x * 32, s0 = blockIdx.y * 32;
  int tx = threadIdx.x & 31, ty = threadIdx.x >> 5;
  const u16* ib = in + (size_t)b * Sd * (Kvh * Hd) + kh * Hd;  // [s][h], stride Kvh*Hd
  u16* ob = out + (size_t)(b * Kvh + kh) * Hd * Sd;            // [h][s], stride Sd
#pragma unroll
  for (int i = 0; i < 32; i += 8)
    tile[ty + i][tx] = ib[(size_t)(s0 + ty + i) * (Kvh * Hd) + h0 + tx];
  __syncthreads();
#pragma unroll
  for (int i = 0; i < 32; i += 8)
    ob[(size_t)(h0 + ty + i) * Sd + s0 + tx] = tile[tx][ty + i];
}

// ---------------- fused RoPE cos/sin tables (Q and K) ----------------------
__global__ __launch_bounds__(256) void k_rope_tables2(const int* __restrict__ qpos,
                                                      const int* __restrict__ kpos,
                                                      float* __restrict__ cosQ,
                                                      float* __restrict__ sinQ,
                                                      float* __restrict__ cosK,
                                                      float* __restrict__ sinK, int nTab) {
  int idx = blockIdx.x * 256 + threadIdx.x;
  const int* pos = qpos;
  float* cT = cosQ;
  float* sT = sinQ;
  if (idx >= nTab) { idx -= nTab; pos = kpos; cT = cosK; sT = sinK; }
  int i = idx & 63, bt = idx >> 6;
  float p = (float)pos[bt];
  float ts = powf(10000.0f, (float)i * (1.0f / 64.0f));
  float x = p / ts;
  cT[idx] = cosf(x);
  sT[idx] = sinf(x);
}

// ---- fused QKV projection GEMM + RoPE epilogues (T1 XCD-local tiling) -----
// 768 blocks; xcd = bid&7 owns bm rows [4x,4x+4): its A panels (2MB) stay in
// that XCD's L2 and are fetched ONCE (R10->R11: FETCH 149.6MB -> fixed).
// Slot 0..63: Q-proj (bn 0..15) -> RoPE f32 -> Qf.
// Slot 64..95: KV (bn 0..7): bn<4 K head -> RoPE -> bf16 Kb[B][Kvh][S][H];
// bn>=4 V -> bf16 Vb[B*S,512].
__global__ __launch_bounds__(256) void k_gemm_qkv(const u16* __restrict__ Aq,
                                                  const u16* __restrict__ Akv,
                                                  const u16* __restrict__ BtQ,
                                                  const u16* __restrict__ BtKV,
                                                  float* __restrict__ Cq,
                                                  u16* __restrict__ Kb,
                                                  u16* __restrict__ Cv,
                                                  const float* __restrict__ cosQ,
                                                  const float* __restrict__ sinQ,
                                                  const float* __restrict__ cosK,
                                                  const float* __restrict__ sinK) {
  __shared__ u16 lA[128 * 32];
  __shared__ u16 lB[128 * 32];
  int bid0 = blockIdx.x;
  int xcd = bid0 & 7, sl = bid0 >> 3;   // 96 slots per XCD
  int isQ = sl < 64;
  int bm, bn;
  const u16 *A, *Bt;
  if (isQ) {
    bm = xcd * 4 + (sl & 3); bn = sl >> 2;        // bn 0..15
    A = Aq; Bt = BtQ;
  } else {
    int s2 = sl - 64;
    bm = xcd * 4 + (s2 & 3); bn = s2 >> 2;        // bn 0..7
    A = Akv; Bt = BtKV;
  }
  int tid = threadIdx.x;
  int lane = tid & 63, wave = tid >> 6;
  int wr = wave >> 1, wc = wave & 1;
  int e0 = tid * 8;
  int r0 = e0 >> 5, c0 = e0 & 31;
  int lr = lane & 15, hi = lane >> 4;
  int kq = hi * 8;

  const u16* gA = A + (size_t)(bm * 128 + r0) * Dd + c0;
  const u16* gB = Bt + (size_t)(bn * 128 + r0) * Dd + c0;

  f32x4 acc[4][4] = {};

  for (int k0 = 0; k0 < Dd; k0 += 32) {
    __syncthreads();
    __builtin_amdgcn_global_load_lds(
        (const __attribute__((address_space(1))) uint32_t*)(gA + k0),
        (__attribute__((address_space(3))) uint32_t*)&lA[e0], 16, 0, 0);
    __builtin_amdgcn_global_load_lds(
        (const __attribute__((address_space(1))) uint32_t*)(gA + k0 + (size_t)64 * Dd),
        (__attribute__((address_space(3))) uint32_t*)&lA[e0 + 64 * 32], 16, 0, 0);
    __builtin_amdgcn_global_load_lds(
        (const __attribute__((address_space(1))) uint32_t*)(gB + k0),
        (__attribute__((address_space(3))) uint32_t*)&lB[e0], 16, 0, 0);
    __builtin_amdgcn_global_load_lds(
        (const __attribute__((address_space(1))) uint32_t*)(gB + k0 + (size_t)64 * Dd),
        (__attribute__((address_space(3))) uint32_t*)&lB[e0 + 64 * 32], 16, 0, 0);
    __syncthreads();

    bf16x8 af[4], bfr[4];
#pragma unroll
    for (int m = 0; m < 4; ++m)
      af[m] = *(const bf16x8*)&lA[(wr * 64 + m * 16 + lr) * 32 + kq];
#pragma unroll
    for (int n = 0; n < 4; ++n) {
      int rB = (n >> 1) * 64 + wc * 32 + (n & 1) * 16 + lr;  // remapped col
      bfr[n] = *(const bf16x8*)&lB[rB * 32 + kq];
    }
#pragma unroll
    for (int m = 0; m < 4; ++m)
#pragma unroll
      for (int n = 0; n < 4; ++n)
        acc[m][n] = __builtin_amdgcn_mfma_f32_16x16x32_bf16(af[m], bfr[n], acc[m][n], 0, 0, 0);
  }

  int orow0 = bm * 128 + wr * 64 + hi * 4;
  if (isQ) {  // Q: RoPE in f32, store f32 [B*T, Nh*Hd]
    int head = bn;
#pragma unroll
    for (int m = 0; m < 4; ++m)
#pragma unroll
      for (int n = 0; n < 2; ++n) {
        int i = wc * 32 + n * 16 + lr;   // 0..63 within head
#pragma unroll
        for (int q = 0; q < 4; ++q) {
          int r = orow0 + m * 16 + q;
          float c = cosQ[r * 64 + i], s = sinQ[r * 64 + i];
          float x1 = acc[m][n][q], x2 = acc[m][n + 2][q];
          size_t base = (size_t)r * (Nh * Hd) + head * Hd;
          Cq[base + i]      = x1 * c - x2 * s;
          Cq[base + i + 64] = x2 * c + x1 * s;
        }
      }
  } else if (bn < 4) {  // K head bn: RoPE + bf16, layout [B][Kvh][S][H]
    int kh = bn;
#pragma unroll
    for (int m = 0; m < 4; ++m)
#pragma unroll
      for (int n = 0; n < 2; ++n) {
        int i = wc * 32 + n * 16 + lr;
#pragma unroll
        for (int q = 0; q < 4; ++q) {
          int r = orow0 + m * 16 + q;
          int b = r >> 11, s = r & 2047;
          float c = cosK[r * 64 + i], sn = sinK[r * 64 + i];
          float x1 = acc[m][n][q], x2 = acc[m][n + 2][q];
          size_t base = (((size_t)(b * Kvh + kh)) * Sd + s) * Hd;
          Kb[base + i]      = f2bf(x1 * c - x2 * sn);
          Kb[base + i + 64] = f2bf(x2 * c + x1 * sn);
        }
      }
  } else {       // V -> bf16 [B*S, 512]
#pragma unroll
    for (int m = 0; m < 4; ++m)
#pragma unroll
      for (int n = 0; n < 4; ++n) {
        int col = (bn - 4) * 128 + (n >> 1) * 64 + wc * 32 + (n & 1) * 16 + lr;
#pragma unroll
        for (int q = 0; q < 4; ++q)
          Cv[(size_t)(orow0 + m * 16 + q) * 512 + col] = f2bf(acc[m][n][q]);
      }
  }
}

// ------- GEMM C[M,N] = A[M,K]*Bt[N,K]^T (m97, o-proj; T1 XCD tiling) -------
__global__ __launch_bounds__(256) void k_gemm_bt(const u16* __restrict__ A,
                                                 const u16* __restrict__ Bt,
                                                 float* __restrict__ C,
                                                 int M, int Ncols, int Kd) {
  __shared__ u16 lA[128 * 32];
  __shared__ u16 lB[128 * 32];
  int bid0 = blockIdx.x;
  int xcd = bid0 & 7, sl = bid0 >> 3;   // 64 slots per XCD
  int bm = xcd * 4 + (sl & 3);
  int bn = sl >> 2;                      // 0..15
  int tid = threadIdx.x;
  int lane = tid & 63, wave = tid >> 6;
  int wr = wave >> 1, wc = wave & 1;
  int e0 = tid * 8;
  int r0 = e0 >> 5, c0 = e0 & 31;
  int lr = lane & 15, hi = lane >> 4;
  int kq = hi * 8;

  const u16* gA = A + (size_t)(bm * 128 + r0) * Kd + c0;
  const u16* gB = Bt + (size_t)(bn * 128 + r0) * Kd + c0;

  f32x4 acc[4][4] = {};

  for (int k0 = 0; k0 < Kd; k0 += 32) {
    __syncthreads();
    __builtin_amdgcn_global_load_lds(
        (const __attribute__((address_space(1))) uint32_t*)(gA + k0),
        (__attribute__((address_space(3))) uint32_t*)&lA[e0], 16, 0, 0);
    __builtin_amdgcn_global_load_lds(
        (const __attribute__((address_space(1))) uint32_t*)(gA + k0 + (size_t)64 * Kd),
        (__attribute__((address_space(3))) uint32_t*)&lA[e0 + 64 * 32], 16, 0, 0);
    __builtin_amdgcn_global_load_lds(
        (const __attribute__((address_space(1))) uint32_t*)(gB + k0),
        (__attribute__((address_space(3))) uint32_t*)&lB[e0], 16, 0, 0);
    __builtin_amdgcn_global_load_lds(
        (const __attribute__((address_space(1))) uint32_t*)(gB + k0 + (size_t)64 * Kd),
        (__attribute__((address_space(3))) uint32_t*)&lB[e0 + 64 * 32], 16, 0, 0);
    __syncthreads();

    bf16x8 af[4], bfr[4];
#pragma unroll
    for (int m = 0; m < 4; ++m)
      af[m] = *(const bf16x8*)&lA[(wr * 64 + m * 16 + lr) * 32 + kq];
#pragma unroll
    for (int n = 0; n < 4; ++n)
      bfr[n] = *(const bf16x8*)&lB[(wc * 64 + n * 16 + lr) * 32 + kq];
#pragma unroll
    for (int m = 0; m < 4; ++m)
#pragma unroll
      for (int n = 0; n < 4; ++n)
        acc[m][n] = __builtin_amdgcn_mfma_f32_16x16x32_bf16(af[m], bfr[n], acc[m][n], 0, 0, 0);
  }

  int orow0 = bm * 128 + wr * 64 + hi * 4;
  int ocol0 = bn * 128 + wc * 64 + lr;
#pragma unroll
  for (int m = 0; m < 4; ++m)
#pragma unroll
    for (int n = 0; n < 4; ++n)
#pragma unroll
      for (int q = 0; q < 4; ++q)
        C[(size_t)(orow0 + m * 16 + q) * Ncols + ocol0 + n * 16] = acc[m][n][q];
}

// ---------------- causal GQA flash attention (v7: V direct from L2) --------
// R10 structure (swapped QK^T, per-lane softmax, cvt_pk P repack) with V
// staging REMOVED: Vt fragments read straight from L2 (XCD chunk swizzle
// keeps each (b,kh)'s 512KB Vt resident in one XCD L2; m169 lesson: don't
// stage what cache-fits). LDS 72KB -> 40KB => 4 blocks/CU (was 2), and the
// per-tile vmcnt(0) drain halves (K only staged).
// R4: no min-wave launch_bounds. R6: don't interleave pair. R8: VGPR<=128.
__global__ __launch_bounds__(256) void k_attn(const float* __restrict__ Qf,
                                              const u16* __restrict__ K,   // [B][Kvh][S][H]
                                              const u16* __restrict__ Vt,  // [B][Kvh][H][S]
                                              u16* __restrict__ O) {
  __shared__ u16 kv[2][8192];    // per buf: K tile 64x128 (16KB) only
  __shared__ u16 Pl[4][1024];    // per-wave P [16 rows][64 s] bf16, swizzled

  int bid0 = blockIdx.x;                       // 512 blocks, 8 chunks of 64
  int bid = (bid0 & 7) * 64 + (bid0 >> 3);     // chunk c on XCD c: one (b,kh)
  int p = bid & 15, n = (bid >> 4) & 15, b = bid >> 8;
  int kh = n >> 2;  // G = 4
  int tid = threadIdx.x;
  int lane = tid & 63, wave = tid >> 6;
  int lr = lane & 15, hi = lane >> 4;
  int kq = hi * 8;

  const u16* Kbase = K + ((size_t)(b * Kvh + kh)) * Sd * Hd;   // row stride 256B
  const u16* Vbase = Vt + ((size_t)(b * Kvh + kh)) * Hd * Sd;  // row stride 4096B
  u16* Pw = &Pl[wave][0];
  int rxp = (lr & 7) << 4;

  for (int half = 0; half < 2; ++half) {
    int tile = half ? (31 - p) : p;
    int t0 = tile * 64 + wave * 16;
    int myrow = t0 + lr;

    // ---- Q fragments, hi/lo split from f32 (B-operand: col=lr, k=hi*8+jj) -
    bf16x8 qhi[4], qlo[4];
    {
      const float* qrow = Qf + ((size_t)((b * Td + t0 + lr) * Nh + n)) * Hd;
#pragma unroll
      for (int kk = 0; kk < 4; ++kk) {
        float4 a = *(const float4*)(qrow + kk * 32 + kq);
        float4 c = *(const float4*)(qrow + kk * 32 + kq + 4);
        float xs[8] = {a.x, a.y, a.z, a.w, c.x, c.y, c.z, c.w};
#pragma unroll
        for (int jj = 0; jj < 8; ++jj) {
          u16 h = f2bf(xs[jj]);
          qhi[kk][jj] = (short)h;
          qlo[kk][jj] = (short)f2bf(xs[jj] - bf2f(h));
        }
      }
    }

    float m_run = -1e30f;   // per-lane: running max of row lr
    float l_run = 0.f;      // per-lane: running denom of row lr
    f32x4 oacc[8] = {};

    int nst = tile + 1;  // number of 64-wide s-tiles

    // stage K s-tile st into kv[buf]: LDS linear, global source pre-swizzled
    auto STAGE = [&](int st, int buf) {
      int s0 = st * 64;
      char* kb = (char*)&kv[buf][0];
#pragma unroll
      for (int it = 0; it < 4; ++it) {  // K: 16KB
        int o = it * 4096 + tid * 16;
        int r = o >> 8, w = o & 255;
        const u16* src = Kbase + (size_t)(s0 + r) * Hd + ((w ^ ((r & 7) << 4)) >> 1);
        __builtin_amdgcn_global_load_lds(
            (const __attribute__((address_space(1))) uint32_t*)src,
            (__attribute__((address_space(3))) uint32_t*)(kb + o), 16, 0, 0);
      }
    };

    int cur = 0;
    STAGE(0, 0);
    asm volatile("s_waitcnt vmcnt(0)" ::: "memory");
    __syncthreads();

    for (int st = 0; st < nst; ++st) {
      if (st + 1 < nst) STAGE(st + 1, cur ^ 1);
      int s0 = st * 64;
      const char* kb = (const char*)&kv[cur][0];

      // ---- QK^T swapped: sc[j][q] = score(row=lr, s=s0+16j+4hi+q) ----
      f32x4 sc[4] = {};
#pragma unroll
      for (int j = 0; j < 4; ++j) {
        int r = j * 16 + lr;
        int rx = (r & 7) << 4;
#pragma unroll
        for (int kk = 0; kk < 4; ++kk) {
          bf16x8 kf = *(const bf16x8*)(kb + r * 256 + ((kk * 64 + hi * 16) ^ rx));
          sc[j] = __builtin_amdgcn_mfma_f32_16x16x32_bf16(kf, qhi[kk], sc[j], 0, 0, 0);
          sc[j] = __builtin_amdgcn_mfma_f32_16x16x32_bf16(kf, qlo[kk], sc[j], 0, 0, 0);
        }
      }

      // ---- causal mask (lane row = myrow; s varies over regs) ----
      if (s0 + 63 > t0) {
#pragma unroll
        for (int j = 0; j < 4; ++j) {
          if (s0 + j * 16 + 15 > t0) {
            int sb = s0 + j * 16 + hi * 4;
#pragma unroll
            for (int q = 0; q < 4; ++q)
              if (sb + q > myrow) sc[j][q] = -1e30f;
          }
        }
      }

      // ---- online softmax: in-lane tree + xor16/xor32 (T13 defer-max) ----
      float mb;
      {
        float m0 = fmaxf(fmaxf(sc[0][0], sc[0][1]), fmaxf(sc[0][2], sc[0][3]));
        float m1 = fmaxf(fmaxf(sc[1][0], sc[1][1]), fmaxf(sc[1][2], sc[1][3]));
        float m2 = fmaxf(fmaxf(sc[2][0], sc[2][1]), fmaxf(sc[2][2], sc[2][3]));
        float m3 = fmaxf(fmaxf(sc[3][0], sc[3][1]), fmaxf(sc[3][2], sc[3][3]));
        mb = fmaxf(fmaxf(m0, m1), fmaxf(m2, m3));
      }
      mb = fmaxf(mb, __shfl_xor(mb, 16));
      mb = fmaxf(mb, __shfl_xor(mb, 32));
      if (__any(mb > m_run + 8.f)) {
        float mn = fmaxf(m_run, mb);
        float fac = __expf(m_run - mn);
        m_run = mn;
        l_run *= fac;
        float fq[4];
#pragma unroll
        for (int q = 0; q < 4; ++q) fq[q] = __shfl(fac, 20 * hi + q);
#pragma unroll
        for (int hb = 0; hb < 8; ++hb)
#pragma unroll
          for (int q = 0; q < 4; ++q) oacc[hb][q] *= fq[q];
      }
#pragma unroll
      for (int j = 0; j < 4; ++j)
#pragma unroll
        for (int q = 0; q < 4; ++q) sc[j][q] = __expf(sc[j][q] - m_run);
      {
        float ls = ((sc[0][0] + sc[0][1]) + (sc[0][2] + sc[0][3]))
                 + ((sc[1][0] + sc[1][1]) + (sc[1][2] + sc[1][3]))
                 + ((sc[2][0] + sc[2][1]) + (sc[2][2] + sc[2][3]))
                 + ((sc[3][0] + sc[3][1]) + (sc[3][2] + sc[3][3]));
        ls += __shfl_xor(ls, 16);
        ls += __shfl_xor(ls, 32);
        l_run += ls;
      }

      // ---- P repack: cvt_pk pairs -> 4 aligned ds_write_b64, swizzled ----
#pragma unroll
      for (int j = 0; j < 4; ++j) {
        uint2 pk;
        pk.x = cvtpk_bf16(sc[j][0], sc[j][1]);
        pk.y = cvtpk_bf16(sc[j][2], sc[j][3]);
        *(uint2*)((char*)Pw + lr * 128 + ((j * 32 + hi * 8) ^ rxp)) = pk;
      }
      bf16x8 pf[2];
#pragma unroll
      for (int c = 0; c < 2; ++c)
        pf[c] = *(const bf16x8*)((const char*)Pw + lr * 128 + ((c * 64 + hi * 16) ^ rxp));

      // ---- PV: B-fragments direct from L2-resident Vt (no staging) ----
      // lane (lr,hi) reads 16B at row h=hb*16+lr, col s0 + c*32 + hi*8:
      // per wave-read = 16 rows x 64B contiguous segments; addresses are
      // softmax-independent so loads hoist under the VALU chain.
#pragma unroll
      for (int hb = 0; hb < 8; ++hb) {
        int h = hb * 16 + lr;
        const u16* vrow = Vbase + (size_t)h * Sd + s0 + hi * 8;
#pragma unroll
        for (int c = 0; c < 2; ++c) {
          bf16x8 vf = *(const bf16x8*)(vrow + c * 32);
          oacc[hb] = __builtin_amdgcn_mfma_f32_16x16x32_bf16(pf[c], vf, oacc[hb], 0, 0, 0);
        }
      }

      asm volatile("s_waitcnt vmcnt(0)" ::: "memory");
      __syncthreads();
      cur ^= 1;
    }

    // ---- epilogue: broadcast row denoms, normalize, store ----
    float lq[4];
#pragma unroll
    for (int q = 0; q < 4; ++q) lq[q] = __shfl(l_run, 20 * hi + q);
#pragma unroll
    for (int hb = 0; hb < 8; ++hb)
#pragma unroll
      for (int q = 0; q < 4; ++q) {
        float val = oacc[hb][q] / lq[q];
        O[((size_t)((b * Td + t0 + hi * 4 + q) * Nh + n)) * Hd + hb * 16 + lr] = f2bf(val);
      }
  }
}

// ---------------------------------------------------------------------------
extern "C" void kernel_launch(void* const* d_in, const int* in_sizes, int n_in,
                              void* d_out, int out_size, void* d_ws, size_t ws_size,
                              hipStream_t stream) {
  (void)in_sizes; (void)n_in; (void)out_size; (void)ws_size;
  const float* Xq  = (const float*)d_in[0];
  const float* Xkv = (const float*)d_in[1];
  const int* qpos  = (const int*)d_in[2];
  const int* kpos  = (const int*)d_in[3];
  const float* Wq  = (const float*)d_in[4];
  const float* Wk  = (const float*)d_in[5];
  const float* Wv  = (const float*)d_in[6];
  const float* Wo  = (const float*)d_in[7];
  float* out = (float*)d_out;

  char* ws = (char*)d_ws;
  size_t off = 0;
  auto take = [&](size_t bytes) -> char* {
    char* p = ws + off;
    off += (bytes + 255) & ~(size_t)255;
    return p;
  };
  const size_t nX   = (size_t)Bb * Td * Dd;        // 8,388,608
  const size_t nQ   = (size_t)Bb * Td * Nh * Hd;   // 8,388,608
  const size_t nKV  = (size_t)Bb * Sd * Kvh * Hd;  // 2,097,152
  const size_t nTab = (size_t)Bb * Td * 64;        // 262,144

  u16* XqB   = (u16*)take(nX * 2);                     // reused: attn out
  u16* XkvB  = (u16*)take(nX * 2);                     // reused as Vt
  u16* WqT   = (u16*)take((size_t)Nh * Hd * Dd * 2);
  u16* BtKV  = (u16*)take((size_t)(Kvh * Hd * 2) * Dd * 2);  // [1024][2048]
  u16* WoT   = (u16*)take((size_t)Dd * Nh * Hd * 2);
  float* Qf  = (float*)take(nQ * 4);                   // f32 Q (RoPE'd)
  u16* Kb    = (u16*)take(nKV * 2);                    // [B][Kvh][S][H]
  u16* Vb    = (u16*)take(nKV * 2);
  float* cosQ = (float*)take(nTab * 4);
  float* sinQ = (float*)take(nTab * 4);
  float* cosK = (float*)take(nTab * 4);
  float* sinK = (float*)take(nTab * 4);
  // Aliases (lifetimes sequenced):
  u16* attnB = XqB;          // attn output; XqB dead after QKV-proj
  u16* Vt    = XkvB;         // XkvB dead after QKV-proj + transpose_v input Vb

  k_convert2<<<dim3((int)(2 * nX / 8 / 256)), 256, 0, stream>>>(
      Xq, Xkv, XqB, XkvB, (int)(nX / 8));
  k_transpose_w<<<dim3(64, 64, 4), 256, 0, stream>>>(Wq, Wo, Wk, Wv, WqT, WoT, BtKV);
  k_rope_tables2<<<dim3((int)(2 * nTab / 256)), 256, 0, stream>>>(
      qpos, kpos, cosQ, sinQ, cosK, sinK, (int)nTab);

  // fused Q (RoPE f32) + K (RoPE bf16) + V (bf16) projections
  k_gemm_qkv<<<dim3(512 + 256), 256, 0, stream>>>(
      XqB, XkvB, WqT, BtKV, Qf, Kb, Vb, cosQ, sinQ, cosK, sinK);

  k_transpose_v<<<dim3(Hd / 32, Sd / 32, Bb * Kvh), 256, 0, stream>>>(Vb, Vt);

  k_attn<<<dim3(Bb * Nh * 16), 256, 0, stream>>>(Qf, Kb, Vt, attnB);

  k_gemm_bt<<<dim3((Bb * Td / 128) * ((Nh * Hd) / 128)), 256, 0, stream>>>(
      attnB, WoT, out, Bb * Td, Nh * Hd, Dd);
}

// Round 13
// 256.273 us; speedup vs baseline: 1.3000x; 1.3000x over previous
//
#include <hip/hip_runtime.h>
#include <stdint.h>

#define Bb 2
#define Td 2048
#define Sd 2048
#define Dd 2048
#define Nh 16
#define Kvh 4
#define Hd 128
// G = Nh/Kvh = 4

typedef unsigned short u16;
typedef short bf16x8 __attribute__((ext_vector_type(8)));
typedef float f32x4 __attribute__((ext_vector_type(4)));

__device__ __forceinline__ u16 f2bf(float f) {
  union { float f; unsigned u; } v; v.f = f;
  v.u += 0x7FFF + ((v.u >> 16) & 1);   // round-to-nearest-even
  return (u16)(v.u >> 16);
}
__device__ __forceinline__ float bf2f(u16 h) {
  union { unsigned u; float f; } v; v.u = ((unsigned)h) << 16;
  return v.f;
}
// pack two f32 -> one u32 of 2 bf16 (lo in bits 15:0), RNE
__device__ __forceinline__ uint32_t cvtpk_bf16(float lo, float hi2) {
  uint32_t r;
  asm("v_cvt_pk_bf16_f32 %0, %1, %2" : "=v"(r) : "v"(lo), "v"(hi2));
  return r;
}

// ---------------- fused f32 -> bf16 convert for Xq and Xkv -----------------
__global__ __launch_bounds__(256) void k_convert2(const float* __restrict__ in1,
                                                  const float* __restrict__ in2,
                                                  u16* __restrict__ out1,
                                                  u16* __restrict__ out2, int n8each) {
  int i = blockIdx.x * 256 + threadIdx.x;
  const float* in = in1;
  u16* out = out1;
  if (i >= n8each) { i -= n8each; in = in2; out = out2; }
  const float4* p = (const float4*)in;
  float4 a = p[(size_t)i * 2], b = p[(size_t)i * 2 + 1];
  ushort4 r0, r1;
  r0.x = f2bf(a.x); r0.y = f2bf(a.y); r0.z = f2bf(a.z); r0.w = f2bf(a.w);
  r1.x = f2bf(b.x); r1.y = f2bf(b.y); r1.z = f2bf(b.z); r1.w = f2bf(b.w);
  ((ushort4*)out)[(size_t)i * 2] = r0;
  ((ushort4*)out)[(size_t)i * 2 + 1] = r1;
}

// -------- fused weight transposes: z=0 Wq, 1 Wo, 2 Wk, 3 Wv ---------------
__global__ __launch_bounds__(256) void k_transpose_w(const float* __restrict__ Wq,
                                                     const float* __restrict__ Wo,
                                                     const float* __restrict__ Wk,
                                                     const float* __restrict__ Wv,
                                                     u16* __restrict__ WqT,
                                                     u16* __restrict__ WoT,
                                                     u16* __restrict__ BtKV) {
  __shared__ u16 tile[32][33];
  int z = blockIdx.z;
  const float* in;
  u16* out;
  int R, C;
  if (z == 0)      { in = Wq; out = WqT; R = Dd; C = Nh * Hd; }
  else if (z == 1) { in = Wo; out = WoT; R = Nh * Hd; C = Dd; }
  else if (z == 2) { in = Wk; out = BtKV; R = Dd; C = Kvh * Hd; }
  else             { in = Wv; out = BtKV + (size_t)512 * Dd; R = Dd; C = Kvh * Hd; }
  int c0 = blockIdx.x * 32, r0 = blockIdx.y * 32;
  if (c0 >= C) return;
  int tx = threadIdx.x & 31, ty = threadIdx.x >> 5;  // 32 x 8
#pragma unroll
  for (int i = 0; i < 32; i += 8)
    tile[ty + i][tx] = f2bf(in[(size_t)(r0 + ty + i) * C + c0 + tx]);
  __syncthreads();
#pragma unroll
  for (int i = 0; i < 32; i += 8)
    out[(size_t)(c0 + ty + i) * R + r0 + tx] = tile[tx][ty + i];
}

// ---------------- V[B,S,Kvh,H] -> Vt[B,Kvh,H,S] (bf16) ---------------------
__global__ __launch_bounds__(256) void k_transpose_v(const u16* __restrict__ in,
                                                     u16* __restrict__ out) {
  __shared__ u16 tile[32][33];
  int bkh = blockIdx.z;
  int b = bkh >> 2, kh = bkh & 3;
  int h0 = blockIdx.x * 32, s0 = blockIdx.y * 32;
  int tx = threadIdx.x & 31, ty = threadIdx.x >> 5;
  const u16* ib = in + (size_t)b * Sd * (Kvh * Hd) + kh * Hd;  // [s][h], stride Kvh*Hd
  u16* ob = out + (size_t)(b * Kvh + kh) * Hd * Sd;            // [h][s], stride Sd
#pragma unroll
  for (int i = 0; i < 32; i += 8)
    tile[ty + i][tx] = ib[(size_t)(s0 + ty + i) * (Kvh * Hd) + h0 + tx];
  __syncthreads();
#pragma unroll
  for (int i = 0; i < 32; i += 8)
    ob[(size_t)(h0 + ty + i) * Sd + s0 + tx] = tile[tx][ty + i];
}

// ---------------- fused RoPE cos/sin tables (Q and K) ----------------------
__global__ __launch_bounds__(256) void k_rope_tables2(const int* __restrict__ qpos,
                                                      const int* __restrict__ kpos,
                                                      float* __restrict__ cosQ,
                                                      float* __restrict__ sinQ,
                                                      float* __restrict__ cosK,
                                                      float* __restrict__ sinK, int nTab) {
  int idx = blockIdx.x * 256 + threadIdx.x;
  const int* pos = qpos;
  float* cT = cosQ;
  float* sT = sinQ;
  if (idx >= nTab) { idx -= nTab; pos = kpos; cT = cosK; sT = sinK; }
  int i = idx & 63, bt = idx >> 6;
  float p = (float)pos[bt];
  float ts = powf(10000.0f, (float)i * (1.0f / 64.0f));
  float x = p / ts;
  cT[idx] = cosf(x);
  sT[idx] = sinf(x);
}

// ---- fused QKV projection GEMM + RoPE epilogues (T1 XCD-local tiling) -----
// 768 blocks; xcd = bid&7 owns bm rows [4x,4x+4): its A panels (2MB) stay in
// that XCD's L2 and are fetched ONCE (R10->R11: FETCH 149.6MB -> fixed).
// Slot 0..63: Q-proj (bn 0..15) -> RoPE f32 -> Qf.
// Slot 64..95: KV (bn 0..7): bn<4 K head -> RoPE -> bf16 Kb[B][Kvh][S][H];
// bn>=4 V -> bf16 Vb[B*S,512].
__global__ __launch_bounds__(256) void k_gemm_qkv(const u16* __restrict__ Aq,
                                                  const u16* __restrict__ Akv,
                                                  const u16* __restrict__ BtQ,
                                                  const u16* __restrict__ BtKV,
                                                  float* __restrict__ Cq,
                                                  u16* __restrict__ Kb,
                                                  u16* __restrict__ Cv,
                                                  const float* __restrict__ cosQ,
                                                  const float* __restrict__ sinQ,
                                                  const float* __restrict__ cosK,
                                                  const float* __restrict__ sinK) {
  __shared__ u16 lA[128 * 32];
  __shared__ u16 lB[128 * 32];
  int bid0 = blockIdx.x;
  int xcd = bid0 & 7, sl = bid0 >> 3;   // 96 slots per XCD
  int isQ = sl < 64;
  int bm, bn;
  const u16 *A, *Bt;
  if (isQ) {
    bm = xcd * 4 + (sl & 3); bn = sl >> 2;        // bn 0..15
    A = Aq; Bt = BtQ;
  } else {
    int s2 = sl - 64;
    bm = xcd * 4 + (s2 & 3); bn = s2 >> 2;        // bn 0..7
    A = Akv; Bt = BtKV;
  }
  int tid = threadIdx.x;
  int lane = tid & 63, wave = tid >> 6;
  int wr = wave >> 1, wc = wave & 1;
  int e0 = tid * 8;
  int r0 = e0 >> 5, c0 = e0 & 31;
  int lr = lane & 15, hi = lane >> 4;
  int kq = hi * 8;

  const u16* gA = A + (size_t)(bm * 128 + r0) * Dd + c0;
  const u16* gB = Bt + (size_t)(bn * 128 + r0) * Dd + c0;

  f32x4 acc[4][4] = {};

  for (int k0 = 0; k0 < Dd; k0 += 32) {
    __syncthreads();
    __builtin_amdgcn_global_load_lds(
        (const __attribute__((address_space(1))) uint32_t*)(gA + k0),
        (__attribute__((address_space(3))) uint32_t*)&lA[e0], 16, 0, 0);
    __builtin_amdgcn_global_load_lds(
        (const __attribute__((address_space(1))) uint32_t*)(gA + k0 + (size_t)64 * Dd),
        (__attribute__((address_space(3))) uint32_t*)&lA[e0 + 64 * 32], 16, 0, 0);
    __builtin_amdgcn_global_load_lds(
        (const __attribute__((address_space(1))) uint32_t*)(gB + k0),
        (__attribute__((address_space(3))) uint32_t*)&lB[e0], 16, 0, 0);
    __builtin_amdgcn_global_load_lds(
        (const __attribute__((address_space(1))) uint32_t*)(gB + k0 + (size_t)64 * Dd),
        (__attribute__((address_space(3))) uint32_t*)&lB[e0 + 64 * 32], 16, 0, 0);
    __syncthreads();

    bf16x8 af[4], bfr[4];
#pragma unroll
    for (int m = 0; m < 4; ++m)
      af[m] = *(const bf16x8*)&lA[(wr * 64 + m * 16 + lr) * 32 + kq];
#pragma unroll
    for (int n = 0; n < 4; ++n) {
      int rB = (n >> 1) * 64 + wc * 32 + (n & 1) * 16 + lr;  // remapped col
      bfr[n] = *(const bf16x8*)&lB[rB * 32 + kq];
    }
#pragma unroll
    for (int m = 0; m < 4; ++m)
#pragma unroll
      for (int n = 0; n < 4; ++n)
        acc[m][n] = __builtin_amdgcn_mfma_f32_16x16x32_bf16(af[m], bfr[n], acc[m][n], 0, 0, 0);
  }

  int orow0 = bm * 128 + wr * 64 + hi * 4;
  if (isQ) {  // Q: RoPE in f32, store f32 [B*T, Nh*Hd]
    int head = bn;
#pragma unroll
    for (int m = 0; m < 4; ++m)
#pragma unroll
      for (int n = 0; n < 2; ++n) {
        int i = wc * 32 + n * 16 + lr;   // 0..63 within head
#pragma unroll
        for (int q = 0; q < 4; ++q) {
          int r = orow0 + m * 16 + q;
          float c = cosQ[r * 64 + i], s = sinQ[r * 64 + i];
          float x1 = acc[m][n][q], x2 = acc[m][n + 2][q];
          size_t base = (size_t)r * (Nh * Hd) + head * Hd;
          Cq[base + i]      = x1 * c - x2 * s;
          Cq[base + i + 64] = x2 * c + x1 * s;
        }
      }
  } else if (bn < 4) {  // K head bn: RoPE + bf16, layout [B][Kvh][S][H]
    int kh = bn;
#pragma unroll
    for (int m = 0; m < 4; ++m)
#pragma unroll
      for (int n = 0; n < 2; ++n) {
        int i = wc * 32 + n * 16 + lr;
#pragma unroll
        for (int q = 0; q < 4; ++q) {
          int r = orow0 + m * 16 + q;
          int b = r >> 11, s = r & 2047;
          float c = cosK[r * 64 + i], sn = sinK[r * 64 + i];
          float x1 = acc[m][n][q], x2 = acc[m][n + 2][q];
          size_t base = (((size_t)(b * Kvh + kh)) * Sd + s) * Hd;
          Kb[base + i]      = f2bf(x1 * c - x2 * sn);
          Kb[base + i + 64] = f2bf(x2 * c + x1 * sn);
        }
      }
  } else {       // V -> bf16 [B*S, 512]
#pragma unroll
    for (int m = 0; m < 4; ++m)
#pragma unroll
      for (int n = 0; n < 4; ++n) {
        int col = (bn - 4) * 128 + (n >> 1) * 64 + wc * 32 + (n & 1) * 16 + lr;
#pragma unroll
        for (int q = 0; q < 4; ++q)
          Cv[(size_t)(orow0 + m * 16 + q) * 512 + col] = f2bf(acc[m][n][q]);
      }
  }
}

// ------- GEMM C[M,N] = A[M,K]*Bt[N,K]^T (m97, o-proj; T1 XCD tiling) -------
__global__ __launch_bounds__(256) void k_gemm_bt(const u16* __restrict__ A,
                                                 const u16* __restrict__ Bt,
                                                 float* __restrict__ C,
                                                 int M, int Ncols, int Kd) {
  __shared__ u16 lA[128 * 32];
  __shared__ u16 lB[128 * 32];
  int bid0 = blockIdx.x;
  int xcd = bid0 & 7, sl = bid0 >> 3;   // 64 slots per XCD
  int bm = xcd * 4 + (sl & 3);
  int bn = sl >> 2;                      // 0..15
  int tid = threadIdx.x;
  int lane = tid & 63, wave = tid >> 6;
  int wr = wave >> 1, wc = wave & 1;
  int e0 = tid * 8;
  int r0 = e0 >> 5, c0 = e0 & 31;
  int lr = lane & 15, hi = lane >> 4;
  int kq = hi * 8;

  const u16* gA = A + (size_t)(bm * 128 + r0) * Kd + c0;
  const u16* gB = Bt + (size_t)(bn * 128 + r0) * Kd + c0;

  f32x4 acc[4][4] = {};

  for (int k0 = 0; k0 < Kd; k0 += 32) {
    __syncthreads();
    __builtin_amdgcn_global_load_lds(
        (const __attribute__((address_space(1))) uint32_t*)(gA + k0),
        (__attribute__((address_space(3))) uint32_t*)&lA[e0], 16, 0, 0);
    __builtin_amdgcn_global_load_lds(
        (const __attribute__((address_space(1))) uint32_t*)(gA + k0 + (size_t)64 * Kd),
        (__attribute__((address_space(3))) uint32_t*)&lA[e0 + 64 * 32], 16, 0, 0);
    __builtin_amdgcn_global_load_lds(
        (const __attribute__((address_space(1))) uint32_t*)(gB + k0),
        (__attribute__((address_space(3))) uint32_t*)&lB[e0], 16, 0, 0);
    __builtin_amdgcn_global_load_lds(
        (const __attribute__((address_space(1))) uint32_t*)(gB + k0 + (size_t)64 * Kd),
        (__attribute__((address_space(3))) uint32_t*)&lB[e0 + 64 * 32], 16, 0, 0);
    __syncthreads();

    bf16x8 af[4], bfr[4];
#pragma unroll
    for (int m = 0; m < 4; ++m)
      af[m] = *(const bf16x8*)&lA[(wr * 64 + m * 16 + lr) * 32 + kq];
#pragma unroll
    for (int n = 0; n < 4; ++n)
      bfr[n] = *(const bf16x8*)&lB[(wc * 64 + n * 16 + lr) * 32 + kq];
#pragma unroll
    for (int m = 0; m < 4; ++m)
#pragma unroll
      for (int n = 0; n < 4; ++n)
        acc[m][n] = __builtin_amdgcn_mfma_f32_16x16x32_bf16(af[m], bfr[n], acc[m][n], 0, 0, 0);
  }

  int orow0 = bm * 128 + wr * 64 + hi * 4;
  int ocol0 = bn * 128 + wc * 64 + lr;
#pragma unroll
  for (int m = 0; m < 4; ++m)
#pragma unroll
    for (int n = 0; n < 4; ++n)
#pragma unroll
      for (int q = 0; q < 4; ++q)
        C[(size_t)(orow0 + m * 16 + q) * Ncols + ocol0 + n * 16] = acc[m][n][q];
}

// ---------------- causal GQA flash attention (R10/R11-proven, reverted) ----
// Swapped QK^T (mfma(K,Q), lane owns q-row lr): softmax = in-lane tree + 2
// shuffles; P repack = 8 cvt_pk + 4 aligned ds_write_b64. 4 waves x 16
// q-rows; paired tiles {p,31-p}; K AND V double-buffered in LDS (72KB);
// XCD chunk swizzle; T13 defer-max.
// R12 lesson: grid = 512 blocks = 2/CU — LDS cuts below 80KB buy NOTHING
// (occupancy is grid-limited), and V-from-L2 scatter loses to ds_read_b128.
// R4: no min-wave launch_bounds. R6: don't interleave pair. R8: VGPR<=128.
__global__ __launch_bounds__(256) void k_attn(const float* __restrict__ Qf,
                                              const u16* __restrict__ K,   // [B][Kvh][S][H]
                                              const u16* __restrict__ Vt,  // [B][Kvh][H][S]
                                              u16* __restrict__ O) {
  __shared__ u16 kv[2][16384];   // per buf: K tile 64x128 (16KB) | V tile 128x64 (16KB)
  __shared__ u16 Pl[4][1024];    // per-wave P [16 rows][64 s] bf16, swizzled

  int bid0 = blockIdx.x;                       // 512 blocks, 8 chunks of 64
  int bid = (bid0 & 7) * 64 + (bid0 >> 3);     // chunk c on XCD c: one (b,kh)
  int p = bid & 15, n = (bid >> 4) & 15, b = bid >> 8;
  int kh = n >> 2;  // G = 4
  int tid = threadIdx.x;
  int lane = tid & 63, wave = tid >> 6;
  int lr = lane & 15, hi = lane >> 4;
  int kq = hi * 8;

  const u16* Kbase = K + ((size_t)(b * Kvh + kh)) * Sd * Hd;   // row stride 256B
  const u16* Vbase = Vt + ((size_t)(b * Kvh + kh)) * Hd * Sd;  // row stride 4096B
  u16* Pw = &Pl[wave][0];
  int rxp = (lr & 7) << 4;

  for (int half = 0; half < 2; ++half) {
    int tile = half ? (31 - p) : p;
    int t0 = tile * 64 + wave * 16;
    int myrow = t0 + lr;

    // ---- Q fragments, hi/lo split from f32 (B-operand: col=lr, k=hi*8+jj) -
    bf16x8 qhi[4], qlo[4];
    {
      const float* qrow = Qf + ((size_t)((b * Td + t0 + lr) * Nh + n)) * Hd;
#pragma unroll
      for (int kk = 0; kk < 4; ++kk) {
        float4 a = *(const float4*)(qrow + kk * 32 + kq);
        float4 c = *(const float4*)(qrow + kk * 32 + kq + 4);
        float xs[8] = {a.x, a.y, a.z, a.w, c.x, c.y, c.z, c.w};
#pragma unroll
        for (int jj = 0; jj < 8; ++jj) {
          u16 h = f2bf(xs[jj]);
          qhi[kk][jj] = (short)h;
          qlo[kk][jj] = (short)f2bf(xs[jj] - bf2f(h));
        }
      }
    }

    float m_run = -1e30f;   // per-lane: running max of row lr
    float l_run = 0.f;      // per-lane: running denom of row lr
    f32x4 oacc[8] = {};

    int nst = tile + 1;  // number of 64-wide s-tiles

    // stage s-tile st into kv[buf]: LDS linear, global source pre-swizzled
    auto STAGE = [&](int st, int buf) {
      int s0 = st * 64;
      char* kb = (char*)&kv[buf][0];
#pragma unroll
      for (int it = 0; it < 4; ++it) {  // K: 16KB
        int o = it * 4096 + tid * 16;
        int r = o >> 8, w = o & 255;
        const u16* src = Kbase + (size_t)(s0 + r) * Hd + ((w ^ ((r & 7) << 4)) >> 1);
        __builtin_amdgcn_global_load_lds(
            (const __attribute__((address_space(1))) uint32_t*)src,
            (__attribute__((address_space(3))) uint32_t*)(kb + o), 16, 0, 0);
      }
#pragma unroll
      for (int it = 0; it < 4; ++it) {  // V: 16KB
        int o = it * 4096 + tid * 16;
        int h = o >> 7, w = o & 127;
        const u16* src = Vbase + (size_t)h * Sd + s0 + ((w ^ ((h & 7) << 4)) >> 1);
        __builtin_amdgcn_global_load_lds(
            (const __attribute__((address_space(1))) uint32_t*)src,
            (__attribute__((address_space(3))) uint32_t*)(kb + 16384 + o), 16, 0, 0);
      }
    };

    int cur = 0;
    STAGE(0, 0);
    asm volatile("s_waitcnt vmcnt(0)" ::: "memory");
    __syncthreads();

    for (int st = 0; st < nst; ++st) {
      if (st + 1 < nst) STAGE(st + 1, cur ^ 1);
      int s0 = st * 64;
      const char* kb = (const char*)&kv[cur][0];

      // ---- QK^T swapped: sc[j][q] = score(row=lr, s=s0+16j+4hi+q) ----
      f32x4 sc[4] = {};
#pragma unroll
      for (int j = 0; j < 4; ++j) {
        int r = j * 16 + lr;
        int rx = (r & 7) << 4;
#pragma unroll
        for (int kk = 0; kk < 4; ++kk) {
          bf16x8 kf = *(const bf16x8*)(kb + r * 256 + ((kk * 64 + hi * 16) ^ rx));
          sc[j] = __builtin_amdgcn_mfma_f32_16x16x32_bf16(kf, qhi[kk], sc[j], 0, 0, 0);
          sc[j] = __builtin_amdgcn_mfma_f32_16x16x32_bf16(kf, qlo[kk], sc[j], 0, 0, 0);
        }
      }

      // ---- causal mask (lane row = myrow; s varies over regs) ----
      if (s0 + 63 > t0) {
#pragma unroll
        for (int j = 0; j < 4; ++j) {
          if (s0 + j * 16 + 15 > t0) {
            int sb = s0 + j * 16 + hi * 4;
#pragma unroll
            for (int q = 0; q < 4; ++q)
              if (sb + q > myrow) sc[j][q] = -1e30f;
          }
        }
      }

      // ---- online softmax: in-lane tree + xor16/xor32 (T13 defer-max) ----
      float mb;
      {
        float m0 = fmaxf(fmaxf(sc[0][0], sc[0][1]), fmaxf(sc[0][2], sc[0][3]));
        float m1 = fmaxf(fmaxf(sc[1][0], sc[1][1]), fmaxf(sc[1][2], sc[1][3]));
        float m2 = fmaxf(fmaxf(sc[2][0], sc[2][1]), fmaxf(sc[2][2], sc[2][3]));
        float m3 = fmaxf(fmaxf(sc[3][0], sc[3][1]), fmaxf(sc[3][2], sc[3][3]));
        mb = fmaxf(fmaxf(m0, m1), fmaxf(m2, m3));
      }
      mb = fmaxf(mb, __shfl_xor(mb, 16));
      mb = fmaxf(mb, __shfl_xor(mb, 32));
      if (__any(mb > m_run + 8.f)) {
        float mn = fmaxf(m_run, mb);
        float fac = __expf(m_run - mn);
        m_run = mn;
        l_run *= fac;
        float fq[4];
#pragma unroll
        for (int q = 0; q < 4; ++q) fq[q] = __shfl(fac, 20 * hi + q);
#pragma unroll
        for (int hb = 0; hb < 8; ++hb)
#pragma unroll
          for (int q = 0; q < 4; ++q) oacc[hb][q] *= fq[q];
      }
#pragma unroll
      for (int j = 0; j < 4; ++j)
#pragma unroll
        for (int q = 0; q < 4; ++q) sc[j][q] = __expf(sc[j][q] - m_run);
      {
        float ls = ((sc[0][0] + sc[0][1]) + (sc[0][2] + sc[0][3]))
                 + ((sc[1][0] + sc[1][1]) + (sc[1][2] + sc[1][3]))
                 + ((sc[2][0] + sc[2][1]) + (sc[2][2] + sc[2][3]))
                 + ((sc[3][0] + sc[3][1]) + (sc[3][2] + sc[3][3]));
        ls += __shfl_xor(ls, 16);
        ls += __shfl_xor(ls, 32);
        l_run += ls;
      }

      // ---- P repack: cvt_pk pairs -> 4 aligned ds_write_b64, swizzled ----
#pragma unroll
      for (int j = 0; j < 4; ++j) {
        uint2 pk;
        pk.x = cvtpk_bf16(sc[j][0], sc[j][1]);
        pk.y = cvtpk_bf16(sc[j][2], sc[j][3]);
        *(uint2*)((char*)Pw + lr * 128 + ((j * 32 + hi * 8) ^ rxp)) = pk;
      }
      bf16x8 pf[2];
#pragma unroll
      for (int c = 0; c < 2; ++c)
        pf[c] = *(const bf16x8*)((const char*)Pw + lr * 128 + ((c * 64 + hi * 16) ^ rxp));

      // ---- PV from swizzled V tile ----
#pragma unroll
      for (int hb = 0; hb < 8; ++hb) {
        int h = hb * 16 + lr;
        int rx = (h & 7) << 4;
#pragma unroll
        for (int c = 0; c < 2; ++c) {
          bf16x8 vf = *(const bf16x8*)(kb + 16384 + h * 128 + ((c * 64 + hi * 16) ^ rx));
          oacc[hb] = __builtin_amdgcn_mfma_f32_16x16x32_bf16(pf[c], vf, oacc[hb], 0, 0, 0);
        }
      }

      asm volatile("s_waitcnt vmcnt(0)" ::: "memory");
      __syncthreads();
      cur ^= 1;
    }

    // ---- epilogue: broadcast row denoms, normalize, store ----
    float lq[4];
#pragma unroll
    for (int q = 0; q < 4; ++q) lq[q] = __shfl(l_run, 20 * hi + q);
#pragma unroll
    for (int hb = 0; hb < 8; ++hb)
#pragma unroll
      for (int q = 0; q < 4; ++q) {
        float val = oacc[hb][q] / lq[q];
        O[((size_t)((b * Td + t0 + hi * 4 + q) * Nh + n)) * Hd + hb * 16 + lr] = f2bf(val);
      }
  }
}

// ---------------------------------------------------------------------------
extern "C" void kernel_launch(void* const* d_in, const int* in_sizes, int n_in,
                              void* d_out, int out_size, void* d_ws, size_t ws_size,
                              hipStream_t stream) {
  (void)in_sizes; (void)n_in; (void)out_size; (void)ws_size;
  const float* Xq  = (const float*)d_in[0];
  const float* Xkv = (const float*)d_in[1];
  const int* qpos  = (const int*)d_in[2];
  const int* kpos  = (const int*)d_in[3];
  const float* Wq  = (const float*)d_in[4];
  const float* Wk  = (const float*)d_in[5];
  const float* Wv  = (const float*)d_in[6];
  const float* Wo  = (const float*)d_in[7];
  float* out = (float*)d_out;

  char* ws = (char*)d_ws;
  size_t off = 0;
  auto take = [&](size_t bytes) -> char* {
    char* p = ws + off;
    off += (bytes + 255) & ~(size_t)255;
    return p;
  };
  const size_t nX   = (size_t)Bb * Td * Dd;        // 8,388,608
  const size_t nQ   = (size_t)Bb * Td * Nh * Hd;   // 8,388,608
  const size_t nKV  = (size_t)Bb * Sd * Kvh * Hd;  // 2,097,152
  const size_t nTab = (size_t)Bb * Td * 64;        // 262,144

  u16* XqB   = (u16*)take(nX * 2);                     // reused: attn out
  u16* XkvB  = (u16*)take(nX * 2);                     // reused as Vt
  u16* WqT   = (u16*)take((size_t)Nh * Hd * Dd * 2);
  u16* BtKV  = (u16*)take((size_t)(Kvh * Hd * 2) * Dd * 2);  // [1024][2048]
  u16* WoT   = (u16*)take((size_t)Dd * Nh * Hd * 2);
  float* Qf  = (float*)take(nQ * 4);                   // f32 Q (RoPE'd)
  u16* Kb    = (u16*)take(nKV * 2);                    // [B][Kvh][S][H]
  u16* Vb    = (u16*)take(nKV * 2);
  float* cosQ = (float*)take(nTab * 4);
  float* sinQ = (float*)take(nTab * 4);
  float* cosK = (float*)take(nTab * 4);
  float* sinK = (float*)take(nTab * 4);
  // Aliases (lifetimes sequenced):
  u16* attnB = XqB;          // attn output; XqB dead after QKV-proj
  u16* Vt    = XkvB;         // XkvB dead after QKV-proj + transpose_v input Vb

  k_convert2<<<dim3((int)(2 * nX / 8 / 256)), 256, 0, stream>>>(
      Xq, Xkv, XqB, XkvB, (int)(nX / 8));
  k_transpose_w<<<dim3(64, 64, 4), 256, 0, stream>>>(Wq, Wo, Wk, Wv, WqT, WoT, BtKV);
  k_rope_tables2<<<dim3((int)(2 * nTab / 256)), 256, 0, stream>>>(
      qpos, kpos, cosQ, sinQ, cosK, sinK, (int)nTab);

  // fused Q (RoPE f32) + K (RoPE bf16) + V (bf16) projections
  k_gemm_qkv<<<dim3(512 + 256), 256, 0, stream>>>(
      XqB, XkvB, WqT, BtKV, Qf, Kb, Vb, cosQ, sinQ, cosK, sinK);

  k_transpose_v<<<dim3(Hd / 32, Sd / 32, Bb * Kvh), 256, 0, stream>>>(Vb, Vt);

  k_attn<<<dim3(Bb * Nh * 16), 256, 0, stream>>>(Qf, Kb, Vt, attnB);

  k_gemm_bt<<<dim3((Bb * Td / 128) * ((Nh * Hd) / 128)), 256, 0, stream>>>(
      attnB, WoT, out, Bb * Td, Nh * Hd, Dd);
}